// Round 7
// baseline (2927.436 us; speedup 1.0000x reference)
//
#include <hip/hip_runtime.h>
#include <hip/hip_bf16.h>
#include <math.h>

typedef unsigned short u16;
typedef unsigned long long u64;
typedef __attribute__((ext_vector_type(8))) short short8;
typedef __attribute__((ext_vector_type(4))) float f32x4;
typedef __attribute__((ext_vector_type(8))) _Float16 half8;
typedef __attribute__((ext_vector_type(2))) _Float16 half2v;

static __device__ __forceinline__ u16 f2h(float x) {
  _Float16 h = (_Float16)x;
  u16 u;
  __builtin_memcpy(&u, &h, 2);
  return u;
}
static __device__ __forceinline__ float h2f(u16 u) {
  _Float16 h;
  __builtin_memcpy(&h, &u, 2);
  return (float)h;
}
static __device__ __forceinline__ float dot2(unsigned w, unsigned h, float acc) {
  half2v a, b;
  __builtin_memcpy(&a, &w, 4);
  __builtin_memcpy(&b, &h, 4);
#if __has_builtin(__builtin_amdgcn_fdot2)
  return __builtin_amdgcn_fdot2(a, b, acc, false);
#else
  return acc + (float)a[0] * (float)b[0] + (float)a[1] * (float)b[1];
#endif
}

// agent-scope relaxed (cache-bypassing) accessors
static __device__ __forceinline__ float aldf(const float* p) {
  return __hip_atomic_load(const_cast<float*>(p), __ATOMIC_RELAXED, __HIP_MEMORY_SCOPE_AGENT);
}
static __device__ __forceinline__ void astf(float* p, float v) {
  __hip_atomic_store(p, v, __ATOMIC_RELAXED, __HIP_MEMORY_SCOPE_AGENT);
}
static __device__ __forceinline__ u64 ald8(const u64* p) {
  return __hip_atomic_load(const_cast<u64*>(p), __ATOMIC_RELAXED, __HIP_MEMORY_SCOPE_AGENT);
}
static __device__ __forceinline__ void ast32(unsigned* p, unsigned v) {
  __hip_atomic_store(p, v, __ATOMIC_RELAXED, __HIP_MEMORY_SCOPE_AGENT);
}

// ---------------- conversion kernels (f32 -> f16) ----------------

__global__ void cvt_flat(const float* __restrict__ s, u16* __restrict__ d, long n) {
  long i = ((long)blockIdx.x * 256 + threadIdx.x) * 4;
  long stride = (long)gridDim.x * 1024;
  for (; i < n; i += stride) {
    float4 v = *(const float4*)(s + i);
    ushort4 o;
    o.x = f2h(v.x); o.y = f2h(v.y); o.z = f2h(v.z); o.w = f2h(v.w);
    *(ushort4*)(d + i) = o;
  }
}

// pack pairs of f32 -> u32 of 2 f16
__global__ void cvt_packh(const float* __restrict__ s, unsigned* __restrict__ d, long npairs) {
  long i = (long)blockIdx.x * 256 + threadIdx.x;
  long step = (long)gridDim.x * 256;
  for (; i < npairs; i += step) {
    float2 v = *(const float2*)(s + 2 * i);
    d[i] = (unsigned)f2h(v.x) | ((unsigned)f2h(v.y) << 16);
  }
}

__global__ void cvt_strided(const float* __restrict__ s, u16* __restrict__ d,
                            long total, int lshift, long sstride, long soff) {
  long i = (long)blockIdx.x * 256 + threadIdx.x;
  long step = (long)gridDim.x * 256;
  long mask = (1L << lshift) - 1;
  for (; i < total; i += step) {
    long r = i >> lshift;
    long c = i & mask;
    d[i] = f2h(s[r * sstride + soff + c]);
  }
}

__global__ void cvt_x(const float* __restrict__ gt, u16* __restrict__ d) {
  long idx = (long)blockIdx.x * 256 + threadIdx.x;
  if (idx >= 1024L * 512) return;
  long m = idx >> 9;
  int k = (int)(idx & 511);
  if (m < 992) {
    int tt = (int)(m >> 5), b = (int)(m & 31);
    d[idx] = f2h(gt[((long)b * 32 + tt) * 512 + k]);
  } else {
    d[idx] = 0;
  }
}

// ---------------- generic MFMA GEMM (f16): C = A(M,K) * B(N,K)^T ----------------
template<int EPI>
__global__ __launch_bounds__(256)
void gemm_bt(const u16* __restrict__ A, const u16* __restrict__ B,
             void* __restrict__ C0,
             const float* __restrict__ bias, const float* __restrict__ pw,
             int M, int N, int K) {
  __shared__ u16 As[4096];
  __shared__ u16 Bs[4096];
  const int tid = threadIdx.x;
  const int lane = tid & 63, wid = tid >> 6;

  int gx = gridDim.x, gy = gridDim.y;
  int orig = blockIdx.y * gx + blockIdx.x;
  int G = gx < 8 ? gx : 8;
  int ng = gx / G;
  int full = ng * G * gy;
  int ct, rt;
  if (orig < full) {
    int grp = orig / (G * gy), rem = orig % (G * gy);
    ct = grp * G + rem % G;
    rt = rem / G;
  } else {
    int Gt = gx - ng * G;
    int rem = orig - full;
    ct = ng * G + rem % Gt;
    rt = rem / Gt;
  }
  const long row0 = (long)rt * 128;
  const long col0 = (long)ct * 128;

  const int wm = (wid >> 1) * 64, wn = (wid & 1) * 64;
  const int fr = lane & 15, fq = lane >> 4;
  const int sr = wid * 16 + (lane >> 2);
  const int sc = (lane & 3) * 8;

  const u16* Ag0 = A + (row0 + sr) * (long)K + sc;
  const u16* Ag1 = Ag0 + 64 * (long)K;
  const u16* Bg0 = B + (col0 + sr) * (long)K + sc;
  const u16* Bg1 = Bg0 + 64 * (long)K;

  u16* AsW0 = &As[wid * 512];
  u16* AsW1 = &As[2048 + wid * 512];
  u16* BsW0 = &Bs[wid * 512];
  u16* BsW1 = &Bs[2048 + wid * 512];

  f32x4 acc[4][4];
#pragma unroll
  for (int i = 0; i < 4; ++i)
#pragma unroll
    for (int j = 0; j < 4; ++j) acc[i][j] = {0.f, 0.f, 0.f, 0.f};

  for (int k0 = 0; k0 < K; k0 += 32) {
    __builtin_amdgcn_global_load_lds((const __attribute__((address_space(1))) void*)(Ag0 + k0),
                                     (__attribute__((address_space(3))) void*)AsW0, 16, 0, 0);
    __builtin_amdgcn_global_load_lds((const __attribute__((address_space(1))) void*)(Ag1 + k0),
                                     (__attribute__((address_space(3))) void*)AsW1, 16, 0, 0);
    __builtin_amdgcn_global_load_lds((const __attribute__((address_space(1))) void*)(Bg0 + k0),
                                     (__attribute__((address_space(3))) void*)BsW0, 16, 0, 0);
    __builtin_amdgcn_global_load_lds((const __attribute__((address_space(1))) void*)(Bg1 + k0),
                                     (__attribute__((address_space(3))) void*)BsW1, 16, 0, 0);
    __syncthreads();
    half8 af[4], bfv[4];
#pragma unroll
    for (int i = 0; i < 4; ++i) af[i] = *(const half8*)&As[(wm + i * 16 + fr) * 32 + fq * 8];
#pragma unroll
    for (int i = 0; i < 4; ++i) bfv[i] = *(const half8*)&Bs[(wn + i * 16 + fr) * 32 + fq * 8];
#pragma unroll
    for (int i = 0; i < 4; ++i)
#pragma unroll
      for (int j = 0; j < 4; ++j)
        acc[i][j] = __builtin_amdgcn_mfma_f32_16x16x32_f16(af[i], bfv[j], acc[i][j], 0, 0, 0);
    __syncthreads();
  }

#pragma unroll
  for (int i = 0; i < 4; ++i)
#pragma unroll
    for (int j = 0; j < 4; ++j)
#pragma unroll
      for (int q = 0; q < 4; ++q) {
        long gr = row0 + wm + i * 16 + fq * 4 + q;
        long gc = col0 + wn + j * 16 + fr;
        float v = acc[i][j][q];
        if constexpr (EPI == 0) {
          ((u16*)C0)[gr * (long)N + gc] = f2h(v);
        } else if constexpr (EPI == 1) {
          ((u16*)C0)[gr * (long)N + gc] = f2h(tanhf(v + bias[gc]) * pw[gc]);
        } else if constexpr (EPI == 2) {
          if (gr < M) ((float*)C0)[gr * (long)N + gc] = v + bias[gc];
        } else {  // EPI == 3
          if (gr < M) {
            long bb = gr & 31, tt = gr >> 5;
            float o = v + bias[gc];
            __builtin_nontemporal_store(o, &((float*)C0)[(bb * 31 + tt) * (long)N + gc]);
          }
        }
      }
}

// ---------------- persistent recurrence kernel v2 ----------------
// 256 blocks x 512 threads, cooperative. Custom relaxed barrier (r6-proven).
// Per step, 2 phases:
//  GEMV (rg = blk&31, kc = blk>>5): partial[b][kc][r] = Wcat[r, kc-slice].h_t
//    Weights read ONCE per step chip-wide (6.8 MB, ~850 KB/XCD -> L2-resident).
//    h read as f16-packed u32 via UC (2 MB/step). dot2 inner loop.
//  main (b = blk&31, jc = blk>>5): uh=tanh(sum partials), scores vs wvfh
//    (4 b's/XCD -> 256 KB L2), softmax, gm over FWh jc-slice, gh from
//    partials, GRU (h slice persistent in LDS), write h f16-packed UC + Hbuf.
__global__ __launch_bounds__(512)
void persist(const unsigned* __restrict__ WcatH, const float* __restrict__ bcat,
             const u16* __restrict__ wvfh, const u16* __restrict__ FWh,
             const float* __restrict__ GX, const float* __restrict__ pbv,
             const float* __restrict__ h0,
             unsigned* __restrict__ hG32, float* __restrict__ pbuf,
             u16* __restrict__ Hbuf, unsigned* __restrict__ cnt) {
  const int tid = threadIdx.x;
  const int blk = blockIdx.x;
  const int rg = blk & 31, kc = blk >> 5;  // GEMV role
  const int row0 = rg * 104;
  const int b = blk & 31, jc = blk >> 5;   // main role

  __shared__ u64 hA[32][33];     // odd u64 stride: 2-way max bank alias (free)
  __shared__ float uhl[256];
  __shared__ float part[512];
  __shared__ float attnv[128];
  __shared__ float gmp[3][512];
  __shared__ float hl2[128];     // persistent f32 h slice for this (b,jc)

  const float pb0 = pbv[0];

  if (tid < 128) hl2[tid] = h0[b * 1024 + jc * 128 + tid];

  auto xbar = [&](unsigned target) {
    __syncthreads();
    if (tid == 0) {
      __hip_atomic_fetch_add(cnt, 1u, __ATOMIC_RELAXED, __HIP_MEMORY_SCOPE_AGENT);
      while (__hip_atomic_load(cnt, __ATOMIC_RELAXED, __HIP_MEMORY_SCOPE_AGENT) < target) {
        __builtin_amdgcn_s_sleep(2);
      }
    }
    __syncthreads();
  };

  for (int t = 0; t < 31; ++t) {
    // ===== GEMV phase: k-partial gate dots for step t =====
    for (int j = tid; j < 1024; j += 512) {
      int bi = j >> 5, w64 = j & 31;
      hA[bi][w64] = ald8((const u64*)hG32 + (long)bi * 256 + kc * 32 + w64);
    }
    __syncthreads();
    {
      const int bi = tid & 31, rl = tid >> 5;
      unsigned hreg[64];
#pragma unroll
      for (int k = 0; k < 32; ++k) {
        u64 v = hA[bi][k];
        hreg[2 * k] = (unsigned)v;
        hreg[2 * k + 1] = (unsigned)(v >> 32);
      }
#pragma unroll
      for (int jr = 0; jr < 7; ++jr) {
        int r = rl + jr * 16;
        if (r < 104) {
          const unsigned* wr = WcatH + (long)(row0 + r) * 512 + kc * 64;
          float acc = 0.f;
#pragma unroll
          for (int k = 0; k < 64; k += 4) {
            uint4 w4 = *(const uint4*)(wr + k);
            acc = dot2(w4.x, hreg[k], acc);
            acc = dot2(w4.y, hreg[k + 1], acc);
            acc = dot2(w4.z, hreg[k + 2], acc);
            acc = dot2(w4.w, hreg[k + 3], acc);
          }
          astf(pbuf + ((long)bi * 8 + kc) * 3328 + row0 + r, acc);
        }
      }
    }
    xbar(256u * (2 * t + 1));

    // ===== main phase =====
    if (tid < 128) {
      float s0 = bcat[2 * tid], s1 = bcat[2 * tid + 1];
#pragma unroll
      for (int k8 = 0; k8 < 8; ++k8) {
        u64 v = ald8((const u64*)(pbuf + ((long)b * 8 + k8) * 3328) + tid);
        float2 fv;
        __builtin_memcpy(&fv, &v, 8);
        s0 += fv.x;
        s1 += fv.y;
      }
      uhl[2 * tid] = tanhf(s0);
      uhl[2 * tid + 1] = tanhf(s1);
    }
    __syncthreads();
    {
      const int s = tid & 127, q = tid >> 7;
      const u16* wr = wvfh + ((long)(b * 128 + s)) * 256 + q * 64;
      const float* uq = &uhl[q * 64];
      float p = 0.f;
#pragma unroll
      for (int d = 0; d < 64; d += 8) {
        short8 wv = *(const short8*)(wr + d);
#pragma unroll
        for (int e = 0; e < 8; ++e) p += h2f((u16)wv[e]) * uq[d + e];
      }
      part[tid] = p;
    }
    __syncthreads();
    if (tid < 128)
      attnv[tid] = part[tid] + part[tid + 128] + part[tid + 256] + part[tid + 384] + pb0;
    __syncthreads();
    if (tid < 64) {
      float m = fmaxf(attnv[tid], attnv[tid + 64]);
#pragma unroll
      for (int o = 32; o; o >>= 1) m = fmaxf(m, __shfl_xor(m, o));
      float e0 = expf(attnv[tid] - m), e1 = expf(attnv[tid + 64] - m);
      float s2 = e0 + e1;
#pragma unroll
      for (int o = 32; o; o >>= 1) s2 += __shfl_xor(s2, o);
      float inv = 1.f / s2;
      attnv[tid] = e0 * inv;
      attnv[tid + 64] = e1 * inv;
    }
    __syncthreads();
    {
      const int ml = tid & 127, sh = tid >> 7;
      const int col = jc * 128 + ml;
      float g0 = 0.f, g1 = 0.f, g2 = 0.f;
      const u16* fw = FWh + ((long)(b * 128 + sh * 32)) * 3072 + col;
#pragma unroll 4
      for (int s = 0; s < 32; ++s) {
        float a = attnv[sh * 32 + s];
        g0 += a * h2f(fw[0]);
        g1 += a * h2f(fw[1024]);
        g2 += a * h2f(fw[2048]);
        fw += 3072;
      }
      gmp[0][tid] = g0; gmp[1][tid] = g1; gmp[2][tid] = g2;
    }
    __syncthreads();
    if (tid < 128) {
      const int m = jc * 128 + tid;
      float gm0 = gmp[0][tid] + gmp[0][tid + 128] + gmp[0][tid + 256] + gmp[0][tid + 384];
      float gm1 = gmp[1][tid] + gmp[1][tid + 128] + gmp[1][tid + 256] + gmp[1][tid + 384];
      float gm2 = gmp[2][tid] + gmp[2][tid + 128] + gmp[2][tid + 256] + gmp[2][tid + 384];
      float gh0 = bcat[256 + m], gh1 = bcat[1280 + m], gh2 = bcat[2304 + m];
#pragma unroll
      for (int k8 = 0; k8 < 8; ++k8) {
        const float* pk = pbuf + ((long)b * 8 + k8) * 3328;
        gh0 += aldf(pk + 256 + m);
        gh1 += aldf(pk + 1280 + m);
        gh2 += aldf(pk + 2304 + m);
      }
      const long gxo = ((long)t * 32 + b) * 3072;
      float xr = GX[gxo + m] + gm0;
      float xz = GX[gxo + 1024 + m] + gm1;
      float xn = GX[gxo + 2048 + m] + gm2;
      float r = 1.f / (1.f + expf(-(xr + gh0)));
      float z = 1.f / (1.f + expf(-(xz + gh1)));
      float n = tanhf(xn + r * gh2);
      float h2 = (1.f - z) * n + z * hl2[tid];
      hl2[tid] = h2;
      Hbuf[((long)t * 32 + b) * 1024 + m] = f2h(h2);
    }
    __syncthreads();
    if (tid < 64) {
      unsigned pk = (unsigned)f2h(hl2[2 * tid]) | ((unsigned)f2h(hl2[2 * tid + 1]) << 16);
      ast32(hG32 + (long)b * 512 + jc * 64 + tid, pk);
    }
    xbar(256u * (2 * t + 2));
  }
}

// ---------------- launcher ----------------

extern "C" void kernel_launch(void* const* d_in, const int* in_sizes, int n_in,
                              void* d_out, int out_size, void* d_ws, size_t ws_size,
                              hipStream_t stream) {
  const float* f    = (const float*)d_in[0];
  const float* h0   = (const float*)d_in[1];
  const float* gt   = (const float*)d_in[2];
  const float* U_w  = (const float*)d_in[4];
  const float* U_b  = (const float*)d_in[5];
  const float* V_w  = (const float*)d_in[6];
  const float* V_b  = (const float*)d_in[7];
  const float* P_w  = (const float*)d_in[8];
  const float* P_b  = (const float*)d_in[9];
  const float* W_ih = (const float*)d_in[10];
  const float* b_ih = (const float*)d_in[11];
  const float* W_hh = (const float*)d_in[12];
  const float* b_hh = (const float*)d_in[13];
  const float* dw   = (const float*)d_in[14];
  const float* db   = (const float*)d_in[15];

  char* w = (char*)d_ws;
  auto alloc = [&](size_t bytes) { char* p = w; w += (bytes + 255) & ~255ULL; return p; };

  u16*      fbf   = (u16*)alloc(4096L * 1024 * 2);
  u16*      VwH   = (u16*)alloc(256L * 1024 * 2);
  unsigned* WcatH = (unsigned*)alloc(3328L * 512 * 4);  // u32-packed f16 [U_w; W_hh]
  u16*      WxH   = (u16*)alloc(3072L * 512 * 2);
  u16*      WmH   = (u16*)alloc(3072L * 1024 * 2);
  u16*      dwH   = (u16*)alloc(32000L * 1024 * 2);
  u16*      Xh    = (u16*)alloc(1024L * 512 * 2);
  u16*      wvfh  = (u16*)alloc(4096L * 256 * 2);
  float*    GX    = (float*)alloc(1024L * 3072 * 4);
  u16*      FWh   = (u16*)alloc(4096L * 3072 * 2);
  unsigned* hG32  = (unsigned*)alloc(32L * 512 * 4);    // f16-packed h state
  float*    pbuf  = (float*)alloc(32L * 8 * 3328 * 4);
  u16*      Hbuf  = (u16*)alloc(1024L * 1024 * 2);
  float*    bcat  = (float*)alloc(3328L * 4);
  unsigned* cnt   = (unsigned*)alloc(256);

  auto cvg = [](long n) { long g = (n + 1023) / 1024; return (int)(g > 2048 ? 2048 : g); };

  cvt_flat<<<cvg(4194304), 256, 0, stream>>>(f, fbf, 4194304);
  cvt_flat<<<cvg(262144), 256, 0, stream>>>(V_w, VwH, 262144);
  cvt_packh<<<512, 256, 0, stream>>>(U_w, WcatH, 131072);
  cvt_packh<<<2048, 256, 0, stream>>>(W_hh, WcatH + 131072, 1572864);
  cvt_packh<<<64, 256, 0, stream>>>(h0, hG32, 16384);
  cvt_strided<<<2048, 256, 0, stream>>>(W_ih, WxH, 3072L * 512, 9, 1536, 0);
  cvt_strided<<<2048, 256, 0, stream>>>(W_ih, WmH, 3072L * 1024, 10, 1536, 512);
  cvt_flat<<<cvg(32768000), 256, 0, stream>>>(dw, dwH, 32768000);
  cvt_x<<<2048, 256, 0, stream>>>(gt, Xh);
  hipMemcpyAsync(bcat, U_b, 256 * 4, hipMemcpyDeviceToDevice, stream);
  hipMemcpyAsync(bcat + 256, b_hh, 3072 * 4, hipMemcpyDeviceToDevice, stream);
  hipMemsetAsync(cnt, 0, 4, stream);

  // loop-invariant GEMMs (f16)
  gemm_bt<1><<<dim3(2, 32), 256, 0, stream>>>(fbf, VwH, wvfh, V_b, P_w, 4096, 256, 1024);
  gemm_bt<2><<<dim3(24, 8), 256, 0, stream>>>(Xh, WxH, GX, b_ih, nullptr, 992, 3072, 512);
  gemm_bt<0><<<dim3(24, 32), 256, 0, stream>>>(fbf, WmH, FWh, nullptr, nullptr, 4096, 3072, 1024);

  // full recurrence: persistent kernel, replication-free GEMV + f16 dot2
  {
    void* ka[] = {(void*)&WcatH, (void*)&bcat, (void*)&wvfh, (void*)&FWh,
                  (void*)&GX,    (void*)&P_b,  (void*)&h0,   (void*)&hG32,
                  (void*)&pbuf,  (void*)&Hbuf, (void*)&cnt};
    hipLaunchCooperativeKernel((void*)persist, dim3(256), dim3(512), ka, 0, stream);
  }

  // logits
  gemm_bt<3><<<dim3(250, 8), 256, 0, stream>>>(Hbuf, dwH, (float*)d_out, db, nullptr,
                                               992, 32000, 1024);
}